// Round 1
// baseline (203.821 us; speedup 1.0000x reference)
//
#include <hip/hip_runtime.h>

#define EPSF 1e-6f

typedef __bf16 bf16;
typedef bf16 bf16x4 __attribute__((ext_vector_type(4)));
typedef bf16 bf16x8 __attribute__((ext_vector_type(8)));
typedef float f32x4 __attribute__((ext_vector_type(4)));
typedef unsigned int u32;

// N=8, L=S=4096, E=256, H=8, D=32.
// MFMA 16x16x32 bf16 frags: A[m=lane&15][k=(lane>>4)*8+j], B[k][n=lane&15],
// C/D: col=lane&15, row=(lane>>4)*4+reg.
//
// R5 structural change: KfT/VmT global round-trip ELIMINATED. kvproj now
// computes BOTH K and V projections per (coltile, s-tile) block, keeps the
// two 128x128 bf16 tiles in LDS (Vm aliases the dead staging region), and
// accumulates the per-tile partial KV (per head: Kf^T @ Vm over s, k-dim=s)
// plus Ksum partials directly into f32 global buffers via atomicAdd.
// kv_outer + kv_reduce kernels and the 67 MB KfT/VmT + 33 MB part traffic
// are gone. attn reads KV as f32 (256 KB, L2-hot) and converts in-register.

__device__ __forceinline__ void async_ld16(const void* g, void* l) {
    __builtin_amdgcn_global_load_lds(
        (const __attribute__((address_space(1))) u32*)g,
        (__attribute__((address_space(3))) u32*)l, 16, 0, 0);
}

__global__ __launch_bounds__(256) void wconv(
    const float* __restrict__ Wq, const float* __restrict__ Wk,
    const float* __restrict__ Wv, const float* __restrict__ Wm,
    bf16* __restrict__ Wb)
{
    const int b = blockIdx.x, t = threadIdx.x;
    const int m = b >> 6;
    const float* S = (m == 0) ? Wq : (m == 1) ? Wk : (m == 2) ? Wv : Wm;
    const int idx = (b & 63) * 1024 + t * 4;
    float4 v = *(const float4*)(S + idx);
    bf16x4 p = {(bf16)v.x, (bf16)v.y, (bf16)v.z, (bf16)v.w};
    *(bf16x4*)(Wb + (size_t)m * 65536 + idx) = p;
}

// ---------------------------------------------------------------------------
// kvproj (fused): per (coltile, n, s-tile) block computes K-proj tile AND
// V-proj tile (z-loop, staging LDS reused), then partial KV + Ksum via
// in-LDS MFMA and f32 atomicAdd. grid (2, 256), 256 threads.
// LDS: Kf tile [128][136] @0 (34816 B); staging Xs/Ws @34816 (24576 B);
//      Vm tile [128][136] @34816 aliases staging (safe: written only after
//      the z=1 K-loop's final barrier). Total 69632 B -> 2 blocks/CU.
// ---------------------------------------------------------------------------
__global__ __launch_bounds__(256) void kvproj(
    const float* __restrict__ kin, const float* __restrict__ vin,
    const bf16* __restrict__ Wb,
    const float* __restrict__ bk, const float* __restrict__ bv,
    const int* __restrict__ kv_mask,
    float* __restrict__ KVf, float* __restrict__ Ksum)
{
    const int bx = blockIdx.x;                 // coltile (4 heads each)
    const int j0 = bx * 128;
    const int n  = blockIdx.y >> 5;
    const int s0 = (blockIdx.y & 31) * 128;
    const size_t R0 = (size_t)n * 4096 + s0;

    const int t = threadIdx.x, lane = t & 63, w = t >> 6;
    const int ln15 = lane & 15, lg = lane >> 4;
    const int wm = (w >> 1) * 64, wn = (w & 1) * 64;
    const int wbase = t & ~63;

    __shared__ __align__(16) char smem[69632];
    bf16*  Kf_ld = (bf16*)smem;                      // [128 col][136 s]
    float* Xs    = (float*)(smem + 34816);           // 16384 B staging
    bf16*  Ws    = (bf16*)(smem + 34816 + 16384);    //  8192 B staging
    bf16*  Vm_ld = (bf16*)(smem + 34816);            // [128][136], aliases staging

    // kv-mask for this wave's rows (same for K and V phases)
    float mv[4][4];
    #pragma unroll
    for (int mi = 0; mi < 4; ++mi)
        #pragma unroll
        for (int r = 0; r < 4; ++r)
            mv[mi][r] = kv_mask[R0 + wm + mi * 16 + lg * 4 + r] ? 1.f : 0.f;

    #pragma unroll
    for (int z = 0; z < 2; ++z) {
        const float* X    = z ? vin : kin;
        const bf16*  W    = Wb + (size_t)(z + 1) * 65536;   // Wk, Wv
        const float* bias = z ? bv : bk;
        bf16* Yt          = z ? Vm_ld : Kf_ld;

        f32x4 acc[4][4] = {};

        for (int k0 = 0; k0 < 256; k0 += 32) {
            #pragma unroll
            for (int i = 0; i < 4; ++i) {     // X: 1024 16B-slots
                const int c = i * 256 + t, row = c >> 3, sc = c & 7;
                async_ld16(X + (R0 + row) * 256 + k0 + ((sc ^ (row & 7)) * 4),
                           Xs + (size_t)(i * 256 + wbase) * 4);
            }
            #pragma unroll
            for (int i = 0; i < 2; ++i) {     // W: 512 slots, swizzle over row-pairs
                const int c = i * 256 + t, g = c >> 3, c8 = c & 7;
                const int c8s = c8 ^ (g & 7);
                const int wrow = g * 2 + (c8s >> 2), gch = c8s & 3;
                async_ld16(W + (size_t)(j0 + wrow) * 256 + k0 + gch * 8,
                           Ws + (size_t)(i * 256 + wbase) * 8);
            }
            __syncthreads();

            bf16x8 a[4], b[4];
            #pragma unroll
            for (int mi = 0; mi < 4; ++mi) {
                const int r = wm + mi * 16 + ln15, rb = r & 7;
                f32x4 x0 = *(const f32x4*)&Xs[r * 32 + (((lg * 2)     ^ rb) * 4)];
                f32x4 x1 = *(const f32x4*)&Xs[r * 32 + (((lg * 2 + 1) ^ rb) * 4)];
                a[mi] = bf16x8{(bf16)x0[0], (bf16)x0[1], (bf16)x0[2], (bf16)x0[3],
                               (bf16)x1[0], (bf16)x1[1], (bf16)x1[2], (bf16)x1[3]};
            }
            #pragma unroll
            for (int ni = 0; ni < 4; ++ni) {
                const int wr = wn + ni * 16 + ln15, g = wr >> 1;
                const int c8 = ((wr & 1) * 4 + lg) ^ (g & 7);
                b[ni] = *(const bf16x8*)&Ws[g * 64 + c8 * 8];
            }
            #pragma unroll
            for (int mi = 0; mi < 4; ++mi)
                #pragma unroll
                for (int ni = 0; ni < 4; ++ni)
                    acc[mi][ni] = __builtin_amdgcn_mfma_f32_16x16x32_bf16(
                        a[mi], b[ni], acc[mi][ni], 0, 0, 0);
            __syncthreads();
        }

        // epilogue: bias (+elu+1 for K), mask, transpose to [col][s] in LDS.
        // (No /s on Vm: reference's /s and *s cancel; keeping V unscaled
        // preserves bf16 precision — same convention as the R4 kernel.)
        float bb[4];
        #pragma unroll
        for (int ni = 0; ni < 4; ++ni) bb[ni] = bias[j0 + wn + ni * 16 + ln15];
        #pragma unroll
        for (int ni = 0; ni < 4; ++ni) {
            const int col = wn + ni * 16 + ln15;
            #pragma unroll
            for (int mi = 0; mi < 4; ++mi) {
                const int rowb = wm + mi * 16 + lg * 4;
                bf16x4 pk;
                #pragma unroll
                for (int r = 0; r < 4; ++r) {
                    float x = acc[mi][ni][r] + bb[ni];
                    if (z == 0) x = (x > 0.f) ? (x + 1.f) : __expf(x);
                    pk[r] = (bf16)(x * mv[mi][r]);
                }
                *(bf16x4*)&Yt[col * 136 + rowb] = pk;
            }
        }
        __syncthreads();
    }

    // ---- Ksum partial: col-sums over this tile's 128 s-rows ----
    {
        const int c = t >> 1, sh = t & 1;
        const bf16* kp = Kf_ld + c * 136 + sh * 64;
        float s = 0.f;
        #pragma unroll
        for (int j = 0; j < 8; ++j) {
            bf16x8 vv = *(const bf16x8*)(kp + j * 8);
            #pragma unroll
            for (int jj = 0; jj < 8; ++jj) s += (float)vv[jj];
        }
        s += __shfl_xor(s, 1);
        if (sh == 0) atomicAdd(&Ksum[n * 256 + j0 + c], s);
    }

    // ---- partial KV: wave w -> head bx*4+w, 32x32 over k-dim s=128 ----
    {
        const int cb = w * 32;                 // head-local col base in tile
        f32x4 c2[2][2] = {};
        #pragma unroll
        for (int step = 0; step < 4; ++step) {
            const int sb = step * 32 + lg * 8;
            bf16x8 a[2], b[2];
            #pragma unroll
            for (int mi = 0; mi < 2; ++mi)
                a[mi] = *(const bf16x8*)&Kf_ld[(cb + mi * 16 + ln15) * 136 + sb];
            #pragma unroll
            for (int nj = 0; nj < 2; ++nj)
                b[nj] = *(const bf16x8*)&Vm_ld[(cb + nj * 16 + ln15) * 136 + sb];
            #pragma unroll
            for (int mi = 0; mi < 2; ++mi)
                #pragma unroll
                for (int nj = 0; nj < 2; ++nj)
                    c2[mi][nj] = __builtin_amdgcn_mfma_f32_16x16x32_bf16(
                        a[mi], b[nj], c2[mi][nj], 0, 0, 0);
        }
        // D layout: col(v)=ln15, row(d)=lg*4+r. Store [v][d] (v-major),
        // matching what attn's A-frag loads expect.
        float* kvh = KVf + (size_t)((n * 8 + bx * 4 + w) * 1024);
        #pragma unroll
        for (int mi = 0; mi < 2; ++mi)
            #pragma unroll
            for (int nj = 0; nj < 2; ++nj)
                #pragma unroll
                for (int r = 0; r < 4; ++r)
                    atomicAdd(&kvh[(nj * 16 + ln15) * 32 + mi * 16 + lg * 4 + r],
                              c2[mi][nj][r]);
    }
}

// ---------------------------------------------------------------------------
// attn: fused Q-proj (staged core) + linear attention + merge GEMM.
// grid (64, 8), 64-row l-tile, 256 threads. KV now read as f32 (L2-hot,
// 4 KB/head) and converted to bf16 frags in-register.
// ---------------------------------------------------------------------------
__global__ __launch_bounds__(256) void attn(
    const float* __restrict__ qin, const bf16* __restrict__ Wb,
    const float* __restrict__ bq, const int* __restrict__ q_mask,
    const float* __restrict__ KVf, const float* __restrict__ Ksum,
    float* __restrict__ out)
{
    const int n = blockIdx.y, l0 = blockIdx.x * 64;
    const size_t R0 = (size_t)n * 4096 + l0;
    const int t = threadIdx.x, lane = t & 63, w = t >> 6;
    const int ln15 = lane & 15, lg = lane >> 4;
    const int wn = w * 64;
    const int wbase = t & ~63;

    const bf16* Wq = Wb;
    const bf16* Wm = Wb + 3 * 65536;

    __shared__ __align__(16) char smem[33792];
    float* Xs  = (float*)smem;           //  8192 B: q tile 64x32 f32 swizzled
    bf16*  Wst = (bf16*)(smem + 8192);   // 16384 B: Wq tile 256x32 swizzled
    bf16 (*Qs)[264] = (bf16(*)[264])smem;
    __shared__ float KSs[256];
    __shared__ float Dens[64][9];

    KSs[t] = Ksum[n * 256 + t];

    {   // ---- Q-projection, staged ----
        f32x4 acc[4][4] = {};
        for (int k0 = 0; k0 < 256; k0 += 32) {
            #pragma unroll
            for (int i = 0; i < 2; ++i) {     // X: 512 slots
                const int c = i * 256 + t, row = c >> 3, sc = c & 7;
                async_ld16(qin + (R0 + row) * 256 + k0 + ((sc ^ (row & 7)) * 4),
                           Xs + (size_t)(i * 256 + wbase) * 4);
            }
            #pragma unroll
            for (int i = 0; i < 4; ++i) {     // W: 1024 slots (all 256 rows)
                const int c = i * 256 + t, g = c >> 3, c8 = c & 7;
                const int c8s = c8 ^ (g & 7);
                const int wrow = g * 2 + (c8s >> 2), gch = c8s & 3;
                async_ld16(Wq + (size_t)wrow * 256 + k0 + gch * 8,
                           Wst + (size_t)(i * 256 + wbase) * 8);
            }
            __syncthreads();

            bf16x8 a[4], b[4];
            #pragma unroll
            for (int mi = 0; mi < 4; ++mi) {
                const int r = mi * 16 + ln15, rb = r & 7;
                f32x4 x0 = *(const f32x4*)&Xs[r * 32 + (((lg * 2)     ^ rb) * 4)];
                f32x4 x1 = *(const f32x4*)&Xs[r * 32 + (((lg * 2 + 1) ^ rb) * 4)];
                a[mi] = bf16x8{(bf16)x0[0], (bf16)x0[1], (bf16)x0[2], (bf16)x0[3],
                               (bf16)x1[0], (bf16)x1[1], (bf16)x1[2], (bf16)x1[3]};
            }
            #pragma unroll
            for (int ni = 0; ni < 4; ++ni) {
                const int wr = wn + ni * 16 + ln15, g = wr >> 1;
                const int c8 = ((wr & 1) * 4 + lg) ^ (g & 7);
                b[ni] = *(const bf16x8*)&Wst[g * 64 + c8 * 8];
            }
            #pragma unroll
            for (int mi = 0; mi < 4; ++mi)
                #pragma unroll
                for (int ni = 0; ni < 4; ++ni)
                    acc[mi][ni] = __builtin_amdgcn_mfma_f32_16x16x32_bf16(
                        a[mi], b[ni], acc[mi][ni], 0, 0, 0);
            __syncthreads();
        }
        float bb[4];
        #pragma unroll
        for (int ni = 0; ni < 4; ++ni) bb[ni] = bq[wn + ni * 16 + ln15];
        float mv[4][4];
        #pragma unroll
        for (int mi = 0; mi < 4; ++mi)
            #pragma unroll
            for (int r = 0; r < 4; ++r)
                mv[mi][r] = q_mask[R0 + mi * 16 + lg * 4 + r] ? 1.f : 0.f;
        #pragma unroll
        for (int mi = 0; mi < 4; ++mi)
            #pragma unroll
            for (int r = 0; r < 4; ++r) {
                const int row = mi * 16 + lg * 4 + r;
                #pragma unroll
                for (int ni = 0; ni < 4; ++ni) {
                    float x = acc[mi][ni][r] + bb[ni];
                    x = (x > 0.f) ? (x + 1.f) : __expf(x);
                    Qs[row][wn + ni * 16 + ln15] = (bf16)(x * mv[mi][r]);
                }
            }
    }
    __syncthreads();

    #pragma unroll
    for (int i = 0; i < 2; ++i) {   // den[l][h]
        const int idx = t + i * 256;
        const int l = idx & 63, h = idx >> 6;
        float s = 0.f;
        #pragma unroll
        for (int d8 = 0; d8 < 4; ++d8) {
            bf16x8 qv = *(const bf16x8*)&Qs[l][h * 32 + d8 * 8];
            #pragma unroll
            for (int jj = 0; jj < 8; ++jj)
                s += (float)qv[jj] * KSs[h * 32 + d8 * 8 + jj];
        }
        Dens[l][h] = s;
    }
    __syncthreads();

    #pragma unroll
    for (int hh = 0; hh < 2; ++hh) {   // num + normalize (wave-disjoint cols)
        const int h = w * 2 + hh;
        const float* kvh = KVf + (size_t)(n * 8 + h) * 1024;
        bf16x8 a[2], b[4];
        #pragma unroll
        for (int mi = 0; mi < 2; ++mi) {
            const float* ap = kvh + (mi * 16 + ln15) * 32 + lg * 8;
            f32x4 lo = *(const f32x4*)ap;
            f32x4 hi = *(const f32x4*)(ap + 4);
            a[mi] = bf16x8{(bf16)lo[0], (bf16)lo[1], (bf16)lo[2], (bf16)lo[3],
                           (bf16)hi[0], (bf16)hi[1], (bf16)hi[2], (bf16)hi[3]};
        }
        #pragma unroll
        for (int nj = 0; nj < 4; ++nj)
            b[nj] = *(const bf16x8*)&Qs[nj * 16 + ln15][h * 32 + lg * 8];
        f32x4 c[2][4];
        #pragma unroll
        for (int mi = 0; mi < 2; ++mi)
            #pragma unroll
            for (int nj = 0; nj < 4; ++nj) {
                f32x4 zz = {};
                c[mi][nj] = __builtin_amdgcn_mfma_f32_16x16x32_bf16(a[mi], b[nj], zz, 0, 0, 0);
            }
        #pragma unroll
        for (int nj = 0; nj < 4; ++nj) {
            const int l = nj * 16 + ln15;
            const float rcp = 1.f / (Dens[l][h] + EPSF);
            #pragma unroll
            for (int mi = 0; mi < 2; ++mi) {
                bf16x4 pk;
                #pragma unroll
                for (int r = 0; r < 4; ++r) pk[r] = (bf16)(c[mi][nj][r] * rcp);
                *(bf16x4*)&Qs[l][h * 32 + mi * 16 + lg * 4] = pk;
            }
        }
    }
    __syncthreads();

    {   // merge GEMM: out = Attn @ Wm^T (A from LDS, B from L2-hot Wm)
        f32x4 acc[4][4] = {};
        #pragma unroll 2
        for (int k0 = 0; k0 < 256; k0 += 32) {
            bf16x8 a[4], b[4];
            #pragma unroll
            for (int mi = 0; mi < 4; ++mi)
                a[mi] = *(const bf16x8*)&Qs[mi * 16 + ln15][k0 + lg * 8];
            #pragma unroll
            for (int ni = 0; ni < 4; ++ni)
                b[ni] = *(const bf16x8*)(Wm + (size_t)(wn + ni * 16 + ln15) * 256 + k0 + lg * 8);
            #pragma unroll
            for (int mi = 0; mi < 4; ++mi)
                #pragma unroll
                for (int ni = 0; ni < 4; ++ni)
                    acc[mi][ni] = __builtin_amdgcn_mfma_f32_16x16x32_bf16(
                        a[mi], b[ni], acc[mi][ni], 0, 0, 0);
        }
        #pragma unroll
        for (int ni = 0; ni < 4; ++ni) {
            const int col = wn + ni * 16 + ln15;
            #pragma unroll
            for (int mi = 0; mi < 4; ++mi)
                #pragma unroll
                for (int r = 0; r < 4; ++r)
                    out[(R0 + mi * 16 + lg * 4 + r) * 256 + col] = acc[mi][ni][r];
        }
    }
}

extern "C" void kernel_launch(void* const* d_in, const int* in_sizes, int n_in,
                              void* d_out, int out_size, void* d_ws, size_t ws_size,
                              hipStream_t stream) {
    const float* q      = (const float*)d_in[0];
    const float* k      = (const float*)d_in[1];
    const float* v      = (const float*)d_in[2];
    const int*   q_mask = (const int*)  d_in[3];
    const int*   kv_mask= (const int*)  d_in[4];
    const float* Wq     = (const float*)d_in[5];
    const float* bq     = (const float*)d_in[6];
    const float* Wk     = (const float*)d_in[7];
    const float* bk     = (const float*)d_in[8];
    const float* Wv     = (const float*)d_in[9];
    const float* bv     = (const float*)d_in[10];
    const float* Wm     = (const float*)d_in[11];

    char* ws = (char*)d_ws;
    bf16*  Wb   = (bf16*)ws;                       // 524288 B
    float* KVf  = (float*)(ws + 524288);           // 262144 B (f32, atomic-accumulated)
    float* Ksum = (float*)(ws + 524288 + 262144);  //   8192 B (f32, atomic-accumulated)

    hipMemsetAsync(ws + 524288, 0, 262144 + 8192, stream);

    const dim3 blk(256);
    wconv <<<dim3(256),    blk, 0, stream>>>(Wq, Wk, Wv, Wm, Wb);
    kvproj<<<dim3(2, 256), blk, 0, stream>>>(k, v, Wb, bk, bv, kv_mask, KVf, Ksum);
    attn  <<<dim3(64, 8),  blk, 0, stream>>>(q, Wb, bq, q_mask, KVf, Ksum, (float*)d_out);
}